// Round 1
// baseline (131.795 us; speedup 1.0000x reference)
//
#include <hip/hip_runtime.h>
#include <hip/hip_bf16.h>
#include <cstdint>
#include <cstddef>

using bf16 = __hip_bfloat16;
typedef __attribute__((ext_vector_type(8))) short short8v;
typedef __attribute__((ext_vector_type(4))) float f32x4;

static constexpr int BATCH = 32;
static constexpr int CH    = 512;   // C
static constexpr int CIc   = 256;   // inter channels
static constexpr int NSP   = 1024;  // H*W
#define EPSV 1e-5f

__device__ __forceinline__ bf16 f2bf(float f) { return __float2bfloat16(f); }

// ---------------- weight conversion: wcat = [w_g; w_phi; w_theta] bf16, wWb, biascat ----
__global__ __launch_bounds__(256) void convert_weights(
    const float* __restrict__ wg, const float* __restrict__ wph, const float* __restrict__ wth,
    const float* __restrict__ bg, const float* __restrict__ bph, const float* __restrict__ bth,
    const float* __restrict__ wW,
    bf16* __restrict__ wcat, bf16* __restrict__ wWb, float* __restrict__ biascat)
{
  int i = blockIdx.x * 256 + threadIdx.x;
  const int WSZ = CIc * CH; // 131072
  if (i < WSZ) {
    wcat[i]         = f2bf(wg[i]);
    wcat[WSZ + i]   = f2bf(wph[i]);
    wcat[2*WSZ + i] = f2bf(wth[i]);
    wWb[i]          = f2bf(wW[i]);   // w_W is [512][256] = same element count
  }
  if (i < CIc) {
    biascat[i]        = bg[i];
    biascat[CIc + i]  = bph[i];
    biascat[2*CIc + i]= bth[i];
  }
}

// ---------------- x [B,C,N] fp32 -> xt [B,N,C] bf16 ----------------
__global__ __launch_bounds__(256) void transpose_x_kernel(
    const float* __restrict__ x, bf16* __restrict__ xt)
{
  __shared__ bf16 t[32][34];
  int n0 = blockIdx.x * 32, c0 = blockIdx.y * 32, b = blockIdx.z;
  const float* s = x + (size_t)b * CH * NSP;
  bf16* d = xt + (size_t)b * NSP * CH;
  int tx = threadIdx.x & 31, ty = threadIdx.x >> 5; // ty 0..7
  #pragma unroll
  for (int i = 0; i < 32; i += 8)
    t[ty + i][tx] = f2bf(s[(size_t)(c0 + ty + i) * NSP + n0 + tx]);
  __syncthreads();
  #pragma unroll
  for (int i = 0; i < 32; i += 8)
    d[(size_t)(n0 + ty + i) * CH + c0 + tx] = t[tx][ty + i];
}

// ---------------- NT GEMM: C[M][N] = sum_k A[m][k] * B[n][k]  (both bf16 K-major) -------
// EPI 0: store bf16 C
// EPI 1: +bias[row]; rows <512 -> bf16 C (proj: g,phi); rows >=512 -> transposed bf16 to Tt (thetaT)
// EPI 2: final: fp32 out = acc * (a_c/N) + ((bW-mu)*a_c + beta) + x   (a_c = gamma*rsqrt(var+eps))
template<int EPI>
__global__ __launch_bounds__(256) void gemm_nt(
    const bf16* __restrict__ A, size_t sA,
    const bf16* __restrict__ Bm, size_t sB,
    void* __restrict__ Cm, size_t sC,
    int M, int N, int K,
    const float* __restrict__ bias,
    bf16* __restrict__ Tt, size_t sT,
    const float* __restrict__ bW, const float* __restrict__ gma,
    const float* __restrict__ bta, const float* __restrict__ mu,
    const float* __restrict__ var,
    const float* __restrict__ xres, size_t sX)
{
  __shared__ bf16 As[128 * 64];
  __shared__ bf16 Bs[128 * 64];
  const int b  = blockIdx.z;
  const int m0 = blockIdx.y * 128;
  const int n0 = blockIdx.x * 128;
  const bf16* Ab = A  + (size_t)b * sA;
  const bf16* Bb = Bm + (size_t)b * sB;
  const int tid  = threadIdx.x;
  const int wv   = tid >> 6, lane = tid & 63;
  const int l16  = lane & 15, g4 = lane >> 4;
  const int wr   = wv >> 1,  wc = wv & 1;

  f32x4 acc[4][4];
  #pragma unroll
  for (int i = 0; i < 4; ++i)
    #pragma unroll
    for (int j = 0; j < 4; ++j)
      acc[i][j] = (f32x4){0.f, 0.f, 0.f, 0.f};

  short8v ra[4], rb[4];
  auto load_tile = [&](int ks) {
    #pragma unroll
    for (int i = 0; i < 4; ++i) {
      int s = i * 256 + tid;
      int row = s >> 3, ch8 = (s & 7) << 3;
      ra[i] = *(const short8v*)(Ab + (size_t)(m0 + row) * K + ks + ch8);
      rb[i] = *(const short8v*)(Bb + (size_t)(n0 + row) * K + ks + ch8);
    }
  };

  load_tile(0);
  for (int ks = 0; ks < K; ks += 64) {
    __syncthreads();  // previous compute readers done before overwrite
    #pragma unroll
    for (int i = 0; i < 4; ++i) {
      int s = i * 256 + tid;
      *(short8v*)&As[s * 8] = ra[i];
      *(short8v*)&Bs[s * 8] = rb[i];
    }
    __syncthreads();
    if (ks + 64 < K) load_tile(ks + 64);  // prefetch next tile into regs (overlaps MFMA)
    #pragma unroll
    for (int kk = 0; kk < 2; ++kk) {
      short8v af[4], bfv[4];
      #pragma unroll
      for (int mf = 0; mf < 4; ++mf)
        af[mf] = *(const short8v*)&As[(wr * 64 + mf * 16 + l16) * 64 + kk * 32 + g4 * 8];
      #pragma unroll
      for (int nf = 0; nf < 4; ++nf)
        bfv[nf] = *(const short8v*)&Bs[(wc * 64 + nf * 16 + l16) * 64 + kk * 32 + g4 * 8];
      #pragma unroll
      for (int mf = 0; mf < 4; ++mf)
        #pragma unroll
        for (int nf = 0; nf < 4; ++nf)
          acc[mf][nf] = __builtin_amdgcn_mfma_f32_16x16x32_bf16(af[mf], bfv[nf], acc[mf][nf], 0, 0, 0);
    }
  }

  const int colbase = n0 + wc * 64 + l16;
  const int rowbase = m0 + wr * 64 + g4 * 4;

  if constexpr (EPI == 2) {
    #pragma unroll
    for (int mf = 0; mf < 4; ++mf) {
      #pragma unroll
      for (int j = 0; j < 4; ++j) {
        int row = rowbase + mf * 16 + j;
        float a  = gma[row] * rsqrtf(var[row] + EPSV);
        float bb = (bW[row] - mu[row]) * a + bta[row];
        float sc = a * (1.f / (float)NSP);
        #pragma unroll
        for (int nf = 0; nf < 4; ++nf) {
          int col = colbase + nf * 16;
          ((float*)Cm)[(size_t)b * sC + (size_t)row * N + col] =
              acc[mf][nf][j] * sc + bb + xres[(size_t)b * sX + (size_t)row * N + col];
        }
      }
    }
  } else if constexpr (EPI == 1) {
    if (m0 >= 512) {
      // theta rows: store transposed -> Tt[b][col][row-512], bias included
      #pragma unroll
      for (int mf = 0; mf < 4; ++mf) {
        int rowt0 = (m0 - 512) + wr * 64 + mf * 16 + g4 * 4;
        #pragma unroll
        for (int nf = 0; nf < 4; ++nf) {
          int col = colbase + nf * 16;
          bf16* dst = Tt + (size_t)b * sT + (size_t)col * CIc + rowt0;
          #pragma unroll
          for (int j = 0; j < 4; ++j)
            dst[j] = f2bf(acc[mf][nf][j] + bias[512 + rowt0 + j]);
        }
      }
    } else {
      #pragma unroll
      for (int mf = 0; mf < 4; ++mf)
        #pragma unroll
        for (int j = 0; j < 4; ++j) {
          int row = rowbase + mf * 16 + j;
          float badd = bias[row];
          #pragma unroll
          for (int nf = 0; nf < 4; ++nf) {
            int col = colbase + nf * 16;
            ((bf16*)Cm)[(size_t)b * sC + (size_t)row * N + col] = f2bf(acc[mf][nf][j] + badd);
          }
        }
    }
  } else {
    #pragma unroll
    for (int mf = 0; mf < 4; ++mf)
      #pragma unroll
      for (int j = 0; j < 4; ++j) {
        int row = rowbase + mf * 16 + j;
        #pragma unroll
        for (int nf = 0; nf < 4; ++nf) {
          int col = colbase + nf * 16;
          ((bf16*)Cm)[(size_t)b * sC + (size_t)row * N + col] = f2bf(acc[mf][nf][j]);
        }
      }
  }
}

extern "C" void kernel_launch(void* const* d_in, const int* in_sizes, int n_in,
                              void* d_out, int out_size, void* d_ws, size_t ws_size,
                              hipStream_t stream)
{
  const float* x    = (const float*)d_in[0];
  const float* w_g  = (const float*)d_in[1];
  const float* b_g  = (const float*)d_in[2];
  const float* w_th = (const float*)d_in[3];
  const float* b_th = (const float*)d_in[4];
  const float* w_ph = (const float*)d_in[5];
  const float* b_ph = (const float*)d_in[6];
  const float* w_W  = (const float*)d_in[7];
  const float* b_W  = (const float*)d_in[8];
  const float* gma  = (const float*)d_in[9];
  const float* bta  = (const float*)d_in[10];
  const float* mu   = (const float*)d_in[11];
  const float* var  = (const float*)d_in[12];
  float* out = (float*)d_out;

  // workspace layout (bytes), total ~93 MB
  char* ws = (char*)d_ws;
  bf16* proj = (bf16*)(ws + 0);            // [32][512][1024]  rows: g(0-255), phi(256-511)
  bf16* xt   = (bf16*)(ws + 33554432);     // [32][1024][512]  x^T bf16
  bf16* thT  = (bf16*)(ws + 67108864);     // [32][1024][256]  theta^T
  bf16* S    = (bf16*)(ws + 83886080);     // [32][256][256]   S = phi g^T
  bf16* T    = (bf16*)(ws + 88080384);     // [32][512][256]   T = wW S^T
  bf16* wcat = (bf16*)(ws + 96468992);     // [768][512]
  bf16* wWb  = (bf16*)(ws + 97255424);     // [512][256]
  float* bcat= (float*)(ws + 97517568);    // [768]

  convert_weights<<<512, 256, 0, stream>>>(w_g, w_ph, w_th, b_g, b_ph, b_th, w_W, wcat, wWb, bcat);
  transpose_x_kernel<<<dim3(32, 16, 32), 256, 0, stream>>>(x, xt);

  // K1: proj/thT = Wcat . xt^T + bias   (M=768, N=1024, K=512)
  gemm_nt<1><<<dim3(8, 6, 32), 256, 0, stream>>>(
      wcat, 0, xt, (size_t)NSP * CH, proj, (size_t)CH * NSP,
      768, NSP, CH, bcat, thT, (size_t)NSP * CIc,
      nullptr, nullptr, nullptr, nullptr, nullptr, nullptr, 0);

  // K2: S = phi . g^T   (M=256, N=256, K=1024)
  gemm_nt<0><<<dim3(2, 2, 32), 256, 0, stream>>>(
      proj + 256 * 1024, (size_t)CH * NSP, proj, (size_t)CH * NSP, S, (size_t)CIc * CIc,
      CIc, CIc, NSP, nullptr, nullptr, 0,
      nullptr, nullptr, nullptr, nullptr, nullptr, nullptr, 0);

  // K3: T = wW . S^T    (M=512, N=256, K=256)
  gemm_nt<0><<<dim3(2, 4, 32), 256, 0, stream>>>(
      wWb, 0, S, (size_t)CIc * CIc, T, (size_t)CH * CIc,
      CH, CIc, CIc, nullptr, nullptr, 0,
      nullptr, nullptr, nullptr, nullptr, nullptr, nullptr, 0);

  // K4: out = BN(T . thT^T / N + bW) + x   (M=512, N=1024, K=256)
  gemm_nt<2><<<dim3(8, 4, 32), 256, 0, stream>>>(
      T, (size_t)CH * CIc, thT, (size_t)NSP * CIc, out, (size_t)CH * NSP,
      CH, NSP, CIc, nullptr, nullptr, 0,
      b_W, gma, bta, mu, var, x, (size_t)CH * NSP);
}